// Round 1
// baseline (731.296 us; speedup 1.0000x reference)
//
#include <hip/hip_runtime.h>

#define TTHR 0.001f
#define QSCALE 0.17677669529663687f   // 1/sqrt(32)
#define CAP 16

// ---------------- K1: qkv projection GEMM ----------------
// x:(16384,256) @ Wc:(256,768) + bc -> scatter into Q,K,V panels [b*32+l*8+h][n][32]
__global__ __launch_bounds__(256) void k_qkv(
    const float* __restrict__ A, const float* __restrict__ W,
    const float* __restrict__ bias, float* __restrict__ Qp,
    float* __restrict__ Kp, float* __restrict__ Vp)
{
  __shared__ float As[16][132];
  __shared__ float Bs[16][132];
  const int tid = threadIdx.x;
  const int tx = tid & 15, ty = tid >> 4;
  const int m0 = (blockIdx.x & 127) << 7;
  const int c0 = (blockIdx.x >> 7) << 7;
  const int ar = tid >> 2, akq = tid & 3;
  const int bkk = tid >> 4, bcq = tid & 15;
  float acc[2][2][4][4] = {};
  for (int k0 = 0; k0 < 256; k0 += 16) {
    float4 a0 = *(const float4*)&A[(m0 + ar) * 256 + k0 + akq * 4];
    float4 a1 = *(const float4*)&A[(m0 + ar + 64) * 256 + k0 + akq * 4];
    float4 b0 = *(const float4*)&W[(k0 + bkk) * 768 + c0 + bcq * 4];
    float4 b1 = *(const float4*)&W[(k0 + bkk) * 768 + c0 + 64 + bcq * 4];
    __syncthreads();
    As[akq * 4 + 0][ar] = a0.x; As[akq * 4 + 1][ar] = a0.y;
    As[akq * 4 + 2][ar] = a0.z; As[akq * 4 + 3][ar] = a0.w;
    As[akq * 4 + 0][ar + 64] = a1.x; As[akq * 4 + 1][ar + 64] = a1.y;
    As[akq * 4 + 2][ar + 64] = a1.z; As[akq * 4 + 3][ar + 64] = a1.w;
    *(float4*)&Bs[bkk][bcq * 4] = b0;
    *(float4*)&Bs[bkk][64 + bcq * 4] = b1;
    __syncthreads();
#pragma unroll
    for (int kk = 0; kk < 16; ++kk) {
      float4 ta0 = *(const float4*)&As[kk][ty * 4];
      float4 ta1 = *(const float4*)&As[kk][64 + ty * 4];
      float4 tb0 = *(const float4*)&Bs[kk][tx * 4];
      float4 tb1 = *(const float4*)&Bs[kk][64 + tx * 4];
      float av[2][4] = {{ta0.x, ta0.y, ta0.z, ta0.w}, {ta1.x, ta1.y, ta1.z, ta1.w}};
      float bv[2][4] = {{tb0.x, tb0.y, tb0.z, tb0.w}, {tb1.x, tb1.y, tb1.z, tb1.w}};
#pragma unroll
      for (int ry = 0; ry < 2; ++ry)
#pragma unroll
        for (int i = 0; i < 4; ++i)
#pragma unroll
          for (int rx = 0; rx < 2; ++rx)
#pragma unroll
            for (int j = 0; j < 4; ++j)
              acc[ry][rx][i][j] = fmaf(av[ry][i], bv[rx][j], acc[ry][rx][i][j]);
    }
  }
#pragma unroll
  for (int ry = 0; ry < 2; ++ry)
#pragma unroll
    for (int i = 0; i < 4; ++i) {
      const int m = m0 + ry * 64 + ty * 4 + i;
      const int b = m >> 12, n = (m >> 2) & 1023, l = m & 3;
#pragma unroll
      for (int rx = 0; rx < 2; ++rx) {
        const int c = c0 + rx * 64 + tx * 4;
        float4 bv = *(const float4*)&bias[c];
        float4 v;
        v.x = acc[ry][rx][i][0] + bv.x;
        v.y = acc[ry][rx][i][1] + bv.y;
        v.z = acc[ry][rx][i][2] + bv.z;
        v.w = acc[ry][rx][i][3] + bv.w;
        const int part = c >> 8, cc = c & 255;
        const int h = cc >> 5, d = cc & 31;
        float* dst;
        if (part == 0) {
          v.x *= QSCALE; v.y *= QSCALE; v.z *= QSCALE; v.w *= QSCALE;
          dst = Qp;
        } else {
          dst = (part == 1) ? Kp : Vp;
        }
        *(float4*)&dst[((b * 32 + l * 8 + h) << 15) + n * 32 + d] = v;
      }
    }
}

// ---------------- K2a: per-(row,level,chunk) exp-sum ----------------
// grid = bh(32) * rowblk(16) * mchunk(8); 1 wave, lane = row
__global__ __launch_bounds__(64) void k_sum(
    const float* __restrict__ Qp, const float* __restrict__ Kp,
    float* __restrict__ psum)
{
  const int wg = blockIdx.x;
  const int mc = wg & 7, rb = (wg >> 3) & 15, bh = wg >> 7;
  const int b = bh >> 3, h = bh & 7;
  const int n = rb * 64 + threadIdx.x;
#pragma unroll 1
  for (int l = 0; l < 4; ++l) {
    const int panel = b * 32 + l * 8 + h;
    const float* qp = Qp + (panel << 15) + n * 32;
    float q[32];
#pragma unroll
    for (int d4 = 0; d4 < 8; ++d4) {
      float4 t = *(const float4*)&qp[d4 * 4];
      q[d4 * 4] = t.x; q[d4 * 4 + 1] = t.y; q[d4 * 4 + 2] = t.z; q[d4 * 4 + 3] = t.w;
    }
    const float* kb = Kp + (panel << 15) + mc * 4096;  // wave-uniform
    float sum = 0.f;
    for (int m = 0; m < 128; m += 2) {
      const float* kp = kb + m * 32;
      float s00 = 0.f, s01 = 0.f, s10 = 0.f, s11 = 0.f;
#pragma unroll
      for (int d = 0; d < 32; d += 4) {
        float4 ka = *(const float4*)&kp[d];
        float4 kc = *(const float4*)&kp[32 + d];
        s00 = fmaf(ka.x, q[d], s00);     s01 = fmaf(ka.y, q[d + 1], s01);
        s00 = fmaf(ka.z, q[d + 2], s00); s01 = fmaf(ka.w, q[d + 3], s01);
        s10 = fmaf(kc.x, q[d], s10);     s11 = fmaf(kc.y, q[d + 1], s11);
        s10 = fmaf(kc.z, q[d + 2], s10); s11 = fmaf(kc.w, q[d + 3], s11);
      }
      sum += __expf(s00 + s01) + __expf(s10 + s11);
    }
    psum[((bh * 4 + l) * 1024 + n) * 8 + mc] = sum;
  }
}

// ---------------- K2b: recompute scores, threshold, product, sparse slots ----
__global__ __launch_bounds__(64) void k_comb(
    const float* __restrict__ Qp, const float* __restrict__ Kp,
    const float* __restrict__ psum, int* __restrict__ ccnt,
    int* __restrict__ cidx, float* __restrict__ cval)
{
  const int wg = blockIdx.x;
  const int mc = wg & 7, rb = (wg >> 3) & 15, bh = wg >> 7;
  const int b = bh >> 3, h = bh & 7;
  const int n = rb * 64 + threadIdx.x;
  float q[4][32];
  float rcp[4];
#pragma unroll
  for (int l = 0; l < 4; ++l) {
    const int panel = b * 32 + l * 8 + h;
    const float* qp = Qp + (panel << 15) + n * 32;
#pragma unroll
    for (int d4 = 0; d4 < 8; ++d4) {
      float4 t = *(const float4*)&qp[d4 * 4];
      q[l][d4 * 4] = t.x; q[l][d4 * 4 + 1] = t.y;
      q[l][d4 * 4 + 2] = t.z; q[l][d4 * 4 + 3] = t.w;
    }
    const float* pp = psum + ((bh * 4 + l) * 1024 + n) * 8;
    float tot = ((pp[0] + pp[1]) + (pp[2] + pp[3])) + ((pp[4] + pp[5]) + (pp[6] + pp[7]));
    rcp[l] = 1.0f / tot;
  }
  const float* kb = Kp + ((b * 32 + h) << 15) + mc * 4096;  // level stride = 8 panels = 1<<18
  const int rowc = (bh << 10) + n;
  const int off = (rowc * 8 + mc) * CAP;
  int cnt = 0;
  for (int m = 0; m < 128; ++m) {
    float t[4];
#pragma unroll
    for (int l = 0; l < 4; ++l) {
      const float* kp = kb + (l << 18) + m * 32;
      float sa = 0.f, sb = 0.f;
#pragma unroll
      for (int d = 0; d < 32; d += 4) {
        float4 kv = *(const float4*)&kp[d];
        sa = fmaf(kv.x, q[l][d], sa);     sb = fmaf(kv.y, q[l][d + 1], sb);
        sa = fmaf(kv.z, q[l][d + 2], sa); sb = fmaf(kv.w, q[l][d + 3], sb);
      }
      t[l] = __expf(sa + sb) * rcp[l] - TTHR;
    }
    if (t[0] > 0.f && t[1] > 0.f && t[2] > 0.f && t[3] > 0.f) {
      if (cnt < CAP) {
        cidx[off + cnt] = mc * 128 + m;
        cval[off + cnt] = (t[0] * t[1]) * (t[2] * t[3]);
        ++cnt;
      }
    }
  }
  ccnt[rowc * 8 + mc] = cnt;
}

// ---------------- K3: sparse PV gather ----------------
// grid = 32768 rows (bh*1024+n); lane covers (l0, d) and (l0+2, d)
__global__ __launch_bounds__(64) void k_pv(
    const float* __restrict__ Vp, const int* __restrict__ ccnt,
    const int* __restrict__ cidx, const float* __restrict__ cval,
    float* __restrict__ ybuf)
{
  const int rowc = blockIdx.x;
  const int bh = rowc >> 10, n = rowc & 1023;
  const int b = bh >> 3, h = bh & 7;
  const int l0 = threadIdx.x >> 5, d = threadIdx.x & 31;
  const float* vA = Vp + ((b * 32 + l0 * 8 + h) << 15) + d;
  const float* vB = vA + (16 << 15);
  float y0 = 0.f, y1 = 0.f;
  for (int mcj = 0; mcj < 8; ++mcj) {
    const int cnt = ccnt[rowc * 8 + mcj];
    const int off = (rowc * 8 + mcj) * CAP;
    for (int i = 0; i < cnt; ++i) {
      const int m = cidx[off + i];
      const float w = cval[off + i];
      y0 = fmaf(w, vA[m * 32], y0);
      y1 = fmaf(w, vB[m * 32], y1);
    }
  }
  float* yp = ybuf + ((b << 10) + n) * 1024 + l0 * 256 + h * 32 + d;
  yp[0] = y0;
  yp[512] = y1;
}

// ---------------- K4: output projection ----------------
// ybuf:(4096,1024) @ Wp:(1024,1024) + bp -> out
__global__ __launch_bounds__(256) void k_proj(
    const float* __restrict__ A, const float* __restrict__ W,
    const float* __restrict__ bias, float* __restrict__ out)
{
  __shared__ float As[16][132];
  __shared__ float Bs[16][132];
  const int tid = threadIdx.x;
  const int tx = tid & 15, ty = tid >> 4;
  const int m0 = (blockIdx.x & 31) << 7;
  const int c0 = (blockIdx.x >> 5) << 7;
  const int ar = tid >> 2, akq = tid & 3;
  const int bkk = tid >> 4, bcq = tid & 15;
  float acc[2][2][4][4] = {};
  for (int k0 = 0; k0 < 1024; k0 += 16) {
    float4 a0 = *(const float4*)&A[(m0 + ar) * 1024 + k0 + akq * 4];
    float4 a1 = *(const float4*)&A[(m0 + ar + 64) * 1024 + k0 + akq * 4];
    float4 b0 = *(const float4*)&W[(k0 + bkk) * 1024 + c0 + bcq * 4];
    float4 b1 = *(const float4*)&W[(k0 + bkk) * 1024 + c0 + 64 + bcq * 4];
    __syncthreads();
    As[akq * 4 + 0][ar] = a0.x; As[akq * 4 + 1][ar] = a0.y;
    As[akq * 4 + 2][ar] = a0.z; As[akq * 4 + 3][ar] = a0.w;
    As[akq * 4 + 0][ar + 64] = a1.x; As[akq * 4 + 1][ar + 64] = a1.y;
    As[akq * 4 + 2][ar + 64] = a1.z; As[akq * 4 + 3][ar + 64] = a1.w;
    *(float4*)&Bs[bkk][bcq * 4] = b0;
    *(float4*)&Bs[bkk][64 + bcq * 4] = b1;
    __syncthreads();
#pragma unroll
    for (int kk = 0; kk < 16; ++kk) {
      float4 ta0 = *(const float4*)&As[kk][ty * 4];
      float4 ta1 = *(const float4*)&As[kk][64 + ty * 4];
      float4 tb0 = *(const float4*)&Bs[kk][tx * 4];
      float4 tb1 = *(const float4*)&Bs[kk][64 + tx * 4];
      float av[2][4] = {{ta0.x, ta0.y, ta0.z, ta0.w}, {ta1.x, ta1.y, ta1.z, ta1.w}};
      float bv[2][4] = {{tb0.x, tb0.y, tb0.z, tb0.w}, {tb1.x, tb1.y, tb1.z, tb1.w}};
#pragma unroll
      for (int ry = 0; ry < 2; ++ry)
#pragma unroll
        for (int i = 0; i < 4; ++i)
#pragma unroll
          for (int rx = 0; rx < 2; ++rx)
#pragma unroll
            for (int j = 0; j < 4; ++j)
              acc[ry][rx][i][j] = fmaf(av[ry][i], bv[rx][j], acc[ry][rx][i][j]);
    }
  }
#pragma unroll
  for (int ry = 0; ry < 2; ++ry)
#pragma unroll
    for (int i = 0; i < 4; ++i) {
      const int m = m0 + ry * 64 + ty * 4 + i;
#pragma unroll
      for (int rx = 0; rx < 2; ++rx) {
        const int c = c0 + rx * 64 + tx * 4;
        float4 bv = *(const float4*)&bias[c];
        float4 v;
        v.x = acc[ry][rx][i][0] + bv.x;
        v.y = acc[ry][rx][i][1] + bv.y;
        v.z = acc[ry][rx][i][2] + bv.z;
        v.w = acc[ry][rx][i][3] + bv.w;
        *(float4*)&out[m * 1024 + c] = v;
      }
    }
}

extern "C" void kernel_launch(void* const* d_in, const int* in_sizes, int n_in,
                              void* d_out, int out_size, void* d_ws, size_t ws_size,
                              hipStream_t stream)
{
  const float* x  = (const float*)d_in[0];
  const float* Wc = (const float*)d_in[1];
  const float* bc = (const float*)d_in[2];
  const float* Wp = (const float*)d_in[3];
  const float* bp = (const float*)d_in[4];
  float* out = (float*)d_out;
  (void)in_sizes; (void)n_in; (void)out_size;

  // workspace layout (floats)
  // Q:0  K:4M  V:8M  psum:12M(1M)  ybuf:13M(4M)  ccnt:17M(256K int)
  // cidx: +262144 (4M int)  cval: +4M (4M float)   total 26,476,544 floats
  if (ws_size < 26476544ull * 4ull) return;
  float* ws = (float*)d_ws;
  float* Q    = ws;
  float* Kp   = ws + 4194304;
  float* Vp   = ws + 8388608;
  float* psum = ws + 12582912;
  float* ybuf = ws + 13631488;
  int*   ccnt = (int*)(ws + 17825792);
  int*   cidx = ccnt + 262144;
  float* cval = (float*)(cidx + 4194304);

  k_qkv<<<dim3(768), dim3(256), 0, stream>>>(x, Wc, bc, Q, Kp, Vp);
  k_sum<<<dim3(4096), dim3(64), 0, stream>>>(Q, Kp, psum);
  k_comb<<<dim3(4096), dim3(64), 0, stream>>>(Q, Kp, psum, ccnt, cidx, cval);
  k_pv<<<dim3(32768), dim3(64), 0, stream>>>(Vp, ccnt, cidx, cval, ybuf);
  k_proj<<<dim3(256), dim3(256), 0, stream>>>(ybuf, Wp, bp, out);
}

// Round 2
// 368.578 us; speedup vs baseline: 1.9841x; 1.9841x over previous
//
#include <hip/hip_runtime.h>

#define TTHR 0.001f
#define QSCALE 0.17677669529663687f   // 1/sqrt(32)
#define CAP 16

typedef _Float16 half4v __attribute__((ext_vector_type(4)));
typedef _Float16 half8v __attribute__((ext_vector_type(8)));
typedef float f32x4 __attribute__((ext_vector_type(4)));

// ---------------- K1: qkv projection GEMM (fp32 VALU) ----------------
// x:(16384,256) @ Wc:(256,768) + bc
//   Q -> split-fp16 panels Qs[panel][n][64] (hi|lo), scaled by QSCALE
//   K -> split-fp16 panels Ks[panel][n][64]
//   V -> fp32 panels Vp[panel][n][32]
// panel = b*32 + l*8 + h
__global__ __launch_bounds__(256) void k_qkv(
    const float* __restrict__ A, const float* __restrict__ W,
    const float* __restrict__ bias, _Float16* __restrict__ Qs,
    _Float16* __restrict__ Ks, float* __restrict__ Vp)
{
  __shared__ float As[16][132];
  __shared__ float Bs[16][132];
  const int tid = threadIdx.x;
  const int tx = tid & 15, ty = tid >> 4;
  const int m0 = (blockIdx.x & 127) << 7;
  const int c0 = (blockIdx.x >> 7) << 7;
  const int ar = tid >> 2, akq = tid & 3;
  const int bkk = tid >> 4, bcq = tid & 15;
  float acc[2][2][4][4] = {};
  for (int k0 = 0; k0 < 256; k0 += 16) {
    float4 a0 = *(const float4*)&A[(m0 + ar) * 256 + k0 + akq * 4];
    float4 a1 = *(const float4*)&A[(m0 + ar + 64) * 256 + k0 + akq * 4];
    float4 b0 = *(const float4*)&W[(k0 + bkk) * 768 + c0 + bcq * 4];
    float4 b1 = *(const float4*)&W[(k0 + bkk) * 768 + c0 + 64 + bcq * 4];
    __syncthreads();
    As[akq * 4 + 0][ar] = a0.x; As[akq * 4 + 1][ar] = a0.y;
    As[akq * 4 + 2][ar] = a0.z; As[akq * 4 + 3][ar] = a0.w;
    As[akq * 4 + 0][ar + 64] = a1.x; As[akq * 4 + 1][ar + 64] = a1.y;
    As[akq * 4 + 2][ar + 64] = a1.z; As[akq * 4 + 3][ar + 64] = a1.w;
    *(float4*)&Bs[bkk][bcq * 4] = b0;
    *(float4*)&Bs[bkk][64 + bcq * 4] = b1;
    __syncthreads();
#pragma unroll
    for (int kk = 0; kk < 16; ++kk) {
      float4 ta0 = *(const float4*)&As[kk][ty * 4];
      float4 ta1 = *(const float4*)&As[kk][64 + ty * 4];
      float4 tb0 = *(const float4*)&Bs[kk][tx * 4];
      float4 tb1 = *(const float4*)&Bs[kk][64 + tx * 4];
      float av[2][4] = {{ta0.x, ta0.y, ta0.z, ta0.w}, {ta1.x, ta1.y, ta1.z, ta1.w}};
      float bv[2][4] = {{tb0.x, tb0.y, tb0.z, tb0.w}, {tb1.x, tb1.y, tb1.z, tb1.w}};
#pragma unroll
      for (int ry = 0; ry < 2; ++ry)
#pragma unroll
        for (int i = 0; i < 4; ++i)
#pragma unroll
          for (int rx = 0; rx < 2; ++rx)
#pragma unroll
            for (int j = 0; j < 4; ++j)
              acc[ry][rx][i][j] = fmaf(av[ry][i], bv[rx][j], acc[ry][rx][i][j]);
    }
  }
#pragma unroll
  for (int ry = 0; ry < 2; ++ry)
#pragma unroll
    for (int i = 0; i < 4; ++i) {
      const int m = m0 + ry * 64 + ty * 4 + i;
      const int b = m >> 12, n = (m >> 2) & 1023, l = m & 3;
#pragma unroll
      for (int rx = 0; rx < 2; ++rx) {
        const int c = c0 + rx * 64 + tx * 4;
        float4 bv = *(const float4*)&bias[c];
        float vx = acc[ry][rx][i][0] + bv.x;
        float vy = acc[ry][rx][i][1] + bv.y;
        float vz = acc[ry][rx][i][2] + bv.z;
        float vw = acc[ry][rx][i][3] + bv.w;
        const int part = c >> 8, cc = c & 255;
        const int h = cc >> 5, d = cc & 31;
        const int panel = b * 32 + l * 8 + h;
        if (part == 2) {
          float4 v = {vx, vy, vz, vw};
          *(float4*)&Vp[(panel << 15) + n * 32 + d] = v;
        } else {
          _Float16* dst;
          if (part == 0) {
            vx *= QSCALE; vy *= QSCALE; vz *= QSCALE; vw *= QSCALE;
            dst = Qs;
          } else {
            dst = Ks;
          }
          half4v hv = {(_Float16)vx, (_Float16)vy, (_Float16)vz, (_Float16)vw};
          half4v lv = {(_Float16)(vx - (float)hv[0]), (_Float16)(vy - (float)hv[1]),
                       (_Float16)(vz - (float)hv[2]), (_Float16)(vw - (float)hv[3])};
          _Float16* base = dst + (panel << 16) + n * 64 + d;
          *(half4v*)base = hv;
          *(half4v*)(base + 32) = lv;
        }
      }
    }
}

// ---- shared helper: stage a 128x64-half tile into LDS, XOR-swizzled ----
// LDS granule (row, x) holds global granule (row, x ^ (row&7)); 16B granules.
// global_load_lds writes linearly (wave base + lane*16), so the SOURCE address
// carries the inverse permutation (self-inverse XOR).
__device__ __forceinline__ void stage_tile(const _Float16* __restrict__ gsrc,
                                           _Float16* lds, int tid)
{
  const int lane = tid & 63;
  const int w = tid >> 6;
#pragma unroll
  for (int r = 0; r < 4; ++r) {
    const int p = (w * 4 + r) * 64 + lane;          // LDS granule 0..1023
    const int row = p >> 3, xg = p & 7;
    const int g = (row << 3) + (xg ^ (row & 7));    // source granule
    __builtin_amdgcn_global_load_lds(
        (const __attribute__((address_space(1))) void*)(gsrc + g * 8),
        (__attribute__((address_space(3))) void*)(lds + (w * 4 + r) * 512),
        16, 0, 0);
  }
}

// ---------------- K2: MFMA scores -> exp -> row sums (Z) ----------------
// grid: panel(128) x rowtile(8) x coltile(8); 256 thr = 2x2 waves of 64x64
__global__ __launch_bounds__(256) void k_score_sum(
    const _Float16* __restrict__ Qs, const _Float16* __restrict__ Ks,
    float* __restrict__ Z)
{
  __shared__ __align__(16) _Float16 Asm[8192];
  __shared__ __align__(16) _Float16 Bsm[8192];
  const int tid = threadIdx.x, lane = tid & 63, w = tid >> 6;
  const int wr = w >> 1, wc = w & 1;
  const int lrow = lane & 15, lk = lane >> 4;
  const int bid = blockIdx.x;
  const int ct = bid & 7, rt = (bid >> 3) & 7, panel = bid >> 6;

  stage_tile(Qs + (panel << 16) + (rt << 13), Asm, tid);
  stage_tile(Ks + (panel << 16) + (ct << 13), Bsm, tid);
  __syncthreads();

  f32x4 acc[4][4] = {};
  const int kstA[3] = {0, 0, 4}, kstB[3] = {0, 4, 0};
#pragma unroll
  for (int ks = 0; ks < 3; ++ks) {
    half8v af[4], bf[4];
#pragma unroll
    for (int mi = 0; mi < 4; ++mi) {
      const int row = (wr << 6) + (mi << 4) + lrow;
      const int xg = (kstA[ks] + lk) ^ (row & 7);
      af[mi] = *(const half8v*)&Asm[((row << 3) + xg) << 3];
    }
#pragma unroll
    for (int ni = 0; ni < 4; ++ni) {
      const int col = (wc << 6) + (ni << 4) + lrow;
      const int xg = (kstB[ks] + lk) ^ (col & 7);
      bf[ni] = *(const half8v*)&Bsm[((col << 3) + xg) << 3];
    }
#pragma unroll
    for (int mi = 0; mi < 4; ++mi)
#pragma unroll
      for (int ni = 0; ni < 4; ++ni)
        acc[mi][ni] = __builtin_amdgcn_mfma_f32_16x16x32_f16(af[mi], bf[ni], acc[mi][ni], 0, 0, 0);
  }

  const int rbase = panel * 1024 + (rt << 7) + (wr << 6);
#pragma unroll
  for (int mi = 0; mi < 4; ++mi) {
#pragma unroll
    for (int reg = 0; reg < 4; ++reg) {
      float s = __expf(acc[mi][0][reg]) + __expf(acc[mi][1][reg]) +
                __expf(acc[mi][2][reg]) + __expf(acc[mi][3][reg]);
      s += __shfl_xor(s, 1, 64);
      s += __shfl_xor(s, 2, 64);
      s += __shfl_xor(s, 4, 64);
      s += __shfl_xor(s, 8, 64);
      if (lrow == 0) atomicAdd(&Z[rbase + (mi << 4) + (lk << 2) + reg], s);
    }
  }
}

// ---------------- K3: MFMA scores x4 levels -> product -> sparse emit ----
// grid: bh(32) x rowtile(8) x coltile(8)
__global__ __launch_bounds__(256) void k_comb2(
    const _Float16* __restrict__ Qs, const _Float16* __restrict__ Ks,
    const float* __restrict__ Z, int* __restrict__ ccnt,
    int* __restrict__ cidx, float* __restrict__ cval)
{
  __shared__ __align__(16) _Float16 Asm[8192];
  __shared__ __align__(16) _Float16 Bsm[8192];
  __shared__ float Zl[128];
  __shared__ int lcnt[128];
  const int tid = threadIdx.x, lane = tid & 63, w = tid >> 6;
  const int wr = w >> 1, wc = w & 1;
  const int lrow = lane & 15, lk = lane >> 4;
  const int bid = blockIdx.x;
  const int ct = bid & 7, rt = (bid >> 3) & 7, bh = bid >> 6;
  const int b = bh >> 3, h = bh & 7;

  if (tid < 128) lcnt[tid] = 0;
  float prod[4][4][4];
#pragma unroll
  for (int mi = 0; mi < 4; ++mi)
#pragma unroll
    for (int ni = 0; ni < 4; ++ni)
#pragma unroll
      for (int r = 0; r < 4; ++r) prod[mi][ni][r] = 1.0f;

#pragma unroll 1
  for (int l = 0; l < 4; ++l) {
    __syncthreads();   // protect LDS from previous level's readers
    const int panel = b * 32 + l * 8 + h;
    stage_tile(Qs + (panel << 16) + (rt << 13), Asm, tid);
    stage_tile(Ks + (panel << 16) + (ct << 13), Bsm, tid);
    if (tid < 128) Zl[tid] = 1.0f / Z[panel * 1024 + (rt << 7) + tid];
    __syncthreads();

    f32x4 acc[4][4] = {};
    const int kstA[3] = {0, 0, 4}, kstB[3] = {0, 4, 0};
#pragma unroll
    for (int ks = 0; ks < 3; ++ks) {
      half8v af[4], bf[4];
#pragma unroll
      for (int mi = 0; mi < 4; ++mi) {
        const int row = (wr << 6) + (mi << 4) + lrow;
        const int xg = (kstA[ks] + lk) ^ (row & 7);
        af[mi] = *(const half8v*)&Asm[((row << 3) + xg) << 3];
      }
#pragma unroll
      for (int ni = 0; ni < 4; ++ni) {
        const int col = (wc << 6) + (ni << 4) + lrow;
        const int xg = (kstB[ks] + lk) ^ (col & 7);
        bf[ni] = *(const half8v*)&Bsm[((col << 3) + xg) << 3];
      }
#pragma unroll
      for (int mi = 0; mi < 4; ++mi)
#pragma unroll
        for (int ni = 0; ni < 4; ++ni)
          acc[mi][ni] = __builtin_amdgcn_mfma_f32_16x16x32_f16(af[mi], bf[ni], acc[mi][ni], 0, 0, 0);
    }

#pragma unroll
    for (int mi = 0; mi < 4; ++mi)
#pragma unroll
      for (int reg = 0; reg < 4; ++reg) {
        const float rcp = Zl[(wr << 6) + (mi << 4) + (lk << 2) + reg];
#pragma unroll
        for (int ni = 0; ni < 4; ++ni) {
          const float e = __expf(acc[mi][ni][reg]) * rcp - TTHR;
          prod[mi][ni][reg] *= fmaxf(e, 0.0f);
        }
      }
  }

  __syncthreads();
#pragma unroll
  for (int mi = 0; mi < 4; ++mi)
#pragma unroll
    for (int ni = 0; ni < 4; ++ni)
#pragma unroll
      for (int reg = 0; reg < 4; ++reg) {
        const float v = prod[mi][ni][reg];
        if (v > 0.0f) {
          const int rloc = (wr << 6) + (mi << 4) + (lk << 2) + reg;
          const int slot = atomicAdd(&lcnt[rloc], 1);
          if (slot < CAP) {
            const int rowc = (bh << 10) + (rt << 7) + rloc;
            const int mglob = (ct << 7) + (wc << 6) + (ni << 4) + lrow;
            cidx[(rowc * 8 + ct) * CAP + slot] = mglob;
            cval[(rowc * 8 + ct) * CAP + slot] = v;
          }
        }
      }
  __syncthreads();
  if (tid < 128) {
    const int rowc = (bh << 10) + (rt << 7) + tid;
    ccnt[rowc * 8 + ct] = min(lcnt[tid], CAP);
  }
}

// ---------------- K4: sparse PV gather ----------------
__global__ __launch_bounds__(64) void k_pv(
    const float* __restrict__ Vp, const int* __restrict__ ccnt,
    const int* __restrict__ cidx, const float* __restrict__ cval,
    float* __restrict__ ybuf)
{
  const int rowc = blockIdx.x;
  const int bh = rowc >> 10, n = rowc & 1023;
  const int b = bh >> 3, h = bh & 7;
  const int l0 = threadIdx.x >> 5, d = threadIdx.x & 31;
  const float* vA = Vp + ((b * 32 + l0 * 8 + h) << 15) + d;
  const float* vB = vA + (16 << 15);
  float y0 = 0.f, y1 = 0.f;
  for (int mcj = 0; mcj < 8; ++mcj) {
    const int cnt = ccnt[rowc * 8 + mcj];
    const int off = (rowc * 8 + mcj) * CAP;
    for (int i = 0; i < cnt; ++i) {
      const int m = cidx[off + i];
      const float w = cval[off + i];
      y0 = fmaf(w, vA[m * 32], y0);
      y1 = fmaf(w, vB[m * 32], y1);
    }
  }
  float* yp = ybuf + ((b << 10) + n) * 1024 + l0 * 256 + h * 32 + d;
  yp[0] = y0;
  yp[512] = y1;
}

// ---------------- K5: output projection (fp32 VALU) ----------------
__global__ __launch_bounds__(256) void k_proj(
    const float* __restrict__ A, const float* __restrict__ W,
    const float* __restrict__ bias, float* __restrict__ out)
{
  __shared__ float As[16][132];
  __shared__ float Bs[16][132];
  const int tid = threadIdx.x;
  const int tx = tid & 15, ty = tid >> 4;
  const int m0 = (blockIdx.x & 31) << 7;
  const int c0 = (blockIdx.x >> 5) << 7;
  const int ar = tid >> 2, akq = tid & 3;
  const int bkk = tid >> 4, bcq = tid & 15;
  float acc[2][2][4][4] = {};
  for (int k0 = 0; k0 < 1024; k0 += 16) {
    float4 a0 = *(const float4*)&A[(m0 + ar) * 1024 + k0 + akq * 4];
    float4 a1 = *(const float4*)&A[(m0 + ar + 64) * 1024 + k0 + akq * 4];
    float4 b0 = *(const float4*)&W[(k0 + bkk) * 1024 + c0 + bcq * 4];
    float4 b1 = *(const float4*)&W[(k0 + bkk) * 1024 + c0 + 64 + bcq * 4];
    __syncthreads();
    As[akq * 4 + 0][ar] = a0.x; As[akq * 4 + 1][ar] = a0.y;
    As[akq * 4 + 2][ar] = a0.z; As[akq * 4 + 3][ar] = a0.w;
    As[akq * 4 + 0][ar + 64] = a1.x; As[akq * 4 + 1][ar + 64] = a1.y;
    As[akq * 4 + 2][ar + 64] = a1.z; As[akq * 4 + 3][ar + 64] = a1.w;
    *(float4*)&Bs[bkk][bcq * 4] = b0;
    *(float4*)&Bs[bkk][64 + bcq * 4] = b1;
    __syncthreads();
#pragma unroll
    for (int kk = 0; kk < 16; ++kk) {
      float4 ta0 = *(const float4*)&As[kk][ty * 4];
      float4 ta1 = *(const float4*)&As[kk][64 + ty * 4];
      float4 tb0 = *(const float4*)&Bs[kk][tx * 4];
      float4 tb1 = *(const float4*)&Bs[kk][64 + tx * 4];
      float av[2][4] = {{ta0.x, ta0.y, ta0.z, ta0.w}, {ta1.x, ta1.y, ta1.z, ta1.w}};
      float bv[2][4] = {{tb0.x, tb0.y, tb0.z, tb0.w}, {tb1.x, tb1.y, tb1.z, tb1.w}};
#pragma unroll
      for (int ry = 0; ry < 2; ++ry)
#pragma unroll
        for (int i = 0; i < 4; ++i)
#pragma unroll
          for (int rx = 0; rx < 2; ++rx)
#pragma unroll
            for (int j = 0; j < 4; ++j)
              acc[ry][rx][i][j] = fmaf(av[ry][i], bv[rx][j], acc[ry][rx][i][j]);
    }
  }
#pragma unroll
  for (int ry = 0; ry < 2; ++ry)
#pragma unroll
    for (int i = 0; i < 4; ++i) {
      const int m = m0 + ry * 64 + ty * 4 + i;
#pragma unroll
      for (int rx = 0; rx < 2; ++rx) {
        const int c = c0 + rx * 64 + tx * 4;
        float4 bv = *(const float4*)&bias[c];
        float4 v;
        v.x = acc[ry][rx][i][0] + bv.x;
        v.y = acc[ry][rx][i][1] + bv.y;
        v.z = acc[ry][rx][i][2] + bv.z;
        v.w = acc[ry][rx][i][3] + bv.w;
        *(float4*)&out[m * 1024 + c] = v;
      }
    }
}

extern "C" void kernel_launch(void* const* d_in, const int* in_sizes, int n_in,
                              void* d_out, int out_size, void* d_ws, size_t ws_size,
                              hipStream_t stream)
{
  const float* x  = (const float*)d_in[0];
  const float* Wc = (const float*)d_in[1];
  const float* bc = (const float*)d_in[2];
  const float* Wp = (const float*)d_in[3];
  const float* bp = (const float*)d_in[4];
  float* out = (float*)d_out;
  (void)in_sizes; (void)n_in; (void)out_size;

  // ws layout (bytes):
  // Vp    @ 0          16 MB  fp32 [128][1024][32]
  // Qs    @ 16777216   16 MB  fp16 [128][1024][64] (hi|lo)
  // Ks    @ 33554432   16 MB
  // Z     @ 50331648   512 KB fp32 [128][1024]
  // ybuf  @ 50855936   16 MB  fp32 [4096][1024]
  // ccnt  @ 67633152   1 MB   int  [32768][8]
  // cidx  @ 68681728   16 MB  int  [32768][8][16]
  // cval  @ 85458944   16 MB  fp32
  if (ws_size < 102236160ull) return;
  char* wsb = (char*)d_ws;
  float*    Vp   = (float*)wsb;
  _Float16* Qs   = (_Float16*)(wsb + 16777216);
  _Float16* Ks   = (_Float16*)(wsb + 33554432);
  float*    Z    = (float*)(wsb + 50331648);
  float*    ybuf = (float*)(wsb + 50855936);
  int*      ccnt = (int*)(wsb + 67633152);
  int*      cidx = (int*)(wsb + 68681728);
  float*    cval = (float*)(wsb + 85458944);

  hipMemsetAsync(Z, 0, 524288, stream);
  k_qkv<<<dim3(768), dim3(256), 0, stream>>>(x, Wc, bc, Qs, Ks, Vp);
  k_score_sum<<<dim3(8192), dim3(256), 0, stream>>>(Qs, Ks, Z);
  k_comb2<<<dim3(2048), dim3(256), 0, stream>>>(Qs, Ks, Z, ccnt, cidx, cval);
  k_pv<<<dim3(32768), dim3(64), 0, stream>>>(Vp, ccnt, cidx, cval, ybuf);
  k_proj<<<dim3(256), dim3(256), 0, stream>>>(ybuf, Wp, bp, out);
}

// Round 3
// 277.674 us; speedup vs baseline: 2.6336x; 1.3274x over previous
//
#include <hip/hip_runtime.h>

#define TTHR 0.001f
#define QSCALE 0.17677669529663687f   // 1/sqrt(32)
#define CAP 16
#define YSCALE 8388608.0f             // 2^23
#define YINV   1.1920928955078125e-07f // 2^-23

typedef _Float16 half4v __attribute__((ext_vector_type(4)));
typedef _Float16 half8v __attribute__((ext_vector_type(8)));
typedef float f32x4 __attribute__((ext_vector_type(4)));

// ---- stage a 128x64-half tile into LDS, XOR-swizzled, arbitrary row stride ----
// LDS granule (row, x) holds source granule (row, x ^ (row&7)); 16B granules.
// global_load_lds writes linearly (wave base + lane*16) -> inverse perm on source.
__device__ __forceinline__ void stage_tile_s(const _Float16* __restrict__ gsrc,
                                             int rowstride, _Float16* lds, int tid)
{
  const int lane = tid & 63;
  const int w4 = (tid >> 6) << 2;
#pragma unroll
  for (int r = 0; r < 4; ++r) {
    const int p = (w4 + r) * 64 + lane;
    const int row = p >> 3, xg = p & 7;
    __builtin_amdgcn_global_load_lds(
        (const __attribute__((address_space(1))) void*)(gsrc + row * rowstride + ((xg ^ (row & 7)) << 3)),
        (__attribute__((address_space(3))) void*)(lds + (w4 + r) * 512),
        16, 0, 0);
  }
}

// ---------------- conversion kernels ----------------
// row-major split: in fp32 [M][K] -> oh/ol fp16 [M][K]
__global__ __launch_bounds__(256) void k_split_rm(
    const float* __restrict__ in, _Float16* __restrict__ oh,
    _Float16* __restrict__ ol, int n4)
{
  const int i = blockIdx.x * 256 + threadIdx.x;
  if (i >= n4) return;
  float4 v = ((const float4*)in)[i];
  half4v h = {(_Float16)v.x, (_Float16)v.y, (_Float16)v.z, (_Float16)v.w};
  half4v l = {(_Float16)(v.x - (float)h[0]), (_Float16)(v.y - (float)h[1]),
              (_Float16)(v.z - (float)h[2]), (_Float16)(v.w - (float)h[3])};
  ((half4v*)oh)[i] = h;
  ((half4v*)ol)[i] = l;
}

// transpose split: in fp32 [K][N] -> oh/ol fp16 [N][K]
__global__ __launch_bounds__(256) void k_split_tr(
    const float* __restrict__ in, _Float16* __restrict__ oh,
    _Float16* __restrict__ ol, int K, int N)
{
  __shared__ float t[32][33];
  const int nb = N >> 5;
  const int n0 = (blockIdx.x % nb) << 5, k0 = (blockIdx.x / nb) << 5;
  const int r = threadIdx.x >> 3, c4 = (threadIdx.x & 7) << 2;
  float4 v = *(const float4*)&in[(k0 + r) * N + n0 + c4];
  t[r][c4] = v.x; t[r][c4 + 1] = v.y; t[r][c4 + 2] = v.z; t[r][c4 + 3] = v.w;
  __syncthreads();
  float a0 = t[c4][r], a1 = t[c4 + 1][r], a2 = t[c4 + 2][r], a3 = t[c4 + 3][r];
  half4v h = {(_Float16)a0, (_Float16)a1, (_Float16)a2, (_Float16)a3};
  half4v l = {(_Float16)(a0 - (float)h[0]), (_Float16)(a1 - (float)h[1]),
              (_Float16)(a2 - (float)h[2]), (_Float16)(a3 - (float)h[3])};
  *(half4v*)&oh[(n0 + r) * K + k0 + c4] = h;
  *(half4v*)&ol[(n0 + r) * K + k0 + c4] = l;
}

// ---------------- generic split-fp16 MFMA GEMM ----------------
// C = A(fp32 via Ah+Al) @ B^T(fp32 via Bh+Bl) ; A:[M][K], B stored [N][K].
// 3 passes: Ah*Bh + Ah*Bl + Al*Bh. 128x128 tile, 4 waves (2x2), 64-half K-chunks.
// EPI 0: out[m*1024+c] = acc*YINV + bias[c]
// EPI 1: qkv scatter (Q/K split-fp16 panels + V fp32 panels)
template<int EPI>
__global__ __launch_bounds__(256) void k_gemm_split(
    const _Float16* __restrict__ Ah, const _Float16* __restrict__ Al,
    const _Float16* __restrict__ Bh, const _Float16* __restrict__ Bl,
    const float* __restrict__ bias, int K, int kclog, int nbn,
    float* __restrict__ out, _Float16* __restrict__ Qs,
    _Float16* __restrict__ Ks, float* __restrict__ Vp)
{
  __shared__ __align__(16) _Float16 Asm[8192];
  __shared__ __align__(16) _Float16 Bsm[8192];
  const int tid = threadIdx.x, lane = tid & 63, w = tid >> 6;
  const int wr = w >> 1, wc = w & 1;
  const int lrow = lane & 15, lk = lane >> 4;
  const int mt = blockIdx.x / nbn, ct = blockIdx.x % nbn;
  const int m0 = mt << 7, c0 = ct << 7;

  f32x4 acc[4][4] = {};
  const int nch = 3 << kclog;
  const int kcm = (1 << kclog) - 1;
#pragma unroll 1
  for (int ch = 0; ch < nch; ++ch) {
    const int phase = ch >> kclog, kc = ch & kcm;
    const _Float16* As = (phase == 2) ? Al : Ah;
    const _Float16* Bs = (phase == 1) ? Bl : Bh;
    __syncthreads();
    stage_tile_s(As + (size_t)m0 * K + (kc << 6), K, Asm, tid);
    stage_tile_s(Bs + (size_t)c0 * K + (kc << 6), K, Bsm, tid);
    __syncthreads();
#pragma unroll
    for (int ks = 0; ks < 2; ++ks) {
      half8v af[4], bf[4];
#pragma unroll
      for (int mi = 0; mi < 4; ++mi) {
        const int row = (wr << 6) + (mi << 4) + lrow;
        const int xg = ((ks << 2) + lk) ^ (row & 7);
        af[mi] = *(const half8v*)&Asm[((row << 3) + xg) << 3];
      }
#pragma unroll
      for (int ni = 0; ni < 4; ++ni) {
        const int col = (wc << 6) + (ni << 4) + lrow;
        const int xg = ((ks << 2) + lk) ^ (col & 7);
        bf[ni] = *(const half8v*)&Bsm[((col << 3) + xg) << 3];
      }
#pragma unroll
      for (int mi = 0; mi < 4; ++mi)
#pragma unroll
        for (int ni = 0; ni < 4; ++ni)
          acc[mi][ni] = __builtin_amdgcn_mfma_f32_16x16x32_f16(af[mi], bf[ni], acc[mi][ni], 0, 0, 0);
    }
  }

#pragma unroll
  for (int ni = 0; ni < 4; ++ni) {
    const int c = c0 + (wc << 6) + (ni << 4) + lrow;
    const float bv = bias[c];
    if (EPI == 0) {
#pragma unroll
      for (int mi = 0; mi < 4; ++mi)
#pragma unroll
        for (int reg = 0; reg < 4; ++reg) {
          const int m = m0 + (wr << 6) + (mi << 4) + (lk << 2) + reg;
          out[m * 1024 + c] = acc[mi][ni][reg] * YINV + bv;
        }
    } else {
      const int part = c >> 8, cc = c & 255;
      const int h = cc >> 5, d = cc & 31;
#pragma unroll
      for (int mi = 0; mi < 4; ++mi)
#pragma unroll
        for (int reg = 0; reg < 4; ++reg) {
          const int m = m0 + (wr << 6) + (mi << 4) + (lk << 2) + reg;
          const int b = m >> 12, n = (m >> 2) & 1023, l = m & 3;
          const int panel = b * 32 + l * 8 + h;
          float v = acc[mi][ni][reg] + bv;
          if (part == 2) {
            Vp[(panel << 15) + n * 32 + d] = v;
          } else {
            _Float16* dst = part ? Ks : Qs;
            if (!part) v *= QSCALE;
            _Float16 hv = (_Float16)v;
            _Float16 lv = (_Float16)(v - (float)hv);
            dst[(panel << 16) + n * 64 + d] = hv;
            dst[(panel << 16) + n * 64 + 32 + d] = lv;
          }
        }
    }
  }
}

// ---------------- K2: MFMA scores -> exp -> row sums (Z) ----------------
__global__ __launch_bounds__(256) void k_score_sum(
    const _Float16* __restrict__ Qs, const _Float16* __restrict__ Ks,
    float* __restrict__ Z)
{
  __shared__ __align__(16) _Float16 Asm[8192];
  __shared__ __align__(16) _Float16 Bsm[8192];
  const int tid = threadIdx.x, lane = tid & 63, w = tid >> 6;
  const int wr = w >> 1, wc = w & 1;
  const int lrow = lane & 15, lk = lane >> 4;
  const int bid = blockIdx.x;
  const int ct = bid & 7, rt = (bid >> 3) & 7, panel = bid >> 6;

  stage_tile_s(Qs + (panel << 16) + (rt << 13), 64, Asm, tid);
  stage_tile_s(Ks + (panel << 16) + (ct << 13), 64, Bsm, tid);
  __syncthreads();

  f32x4 acc[4][4] = {};
  const int kstA[3] = {0, 0, 4}, kstB[3] = {0, 4, 0};
#pragma unroll
  for (int ks = 0; ks < 3; ++ks) {
    half8v af[4], bf[4];
#pragma unroll
    for (int mi = 0; mi < 4; ++mi) {
      const int row = (wr << 6) + (mi << 4) + lrow;
      const int xg = (kstA[ks] + lk) ^ (row & 7);
      af[mi] = *(const half8v*)&Asm[((row << 3) + xg) << 3];
    }
#pragma unroll
    for (int ni = 0; ni < 4; ++ni) {
      const int col = (wc << 6) + (ni << 4) + lrow;
      const int xg = (kstB[ks] + lk) ^ (col & 7);
      bf[ni] = *(const half8v*)&Bsm[((col << 3) + xg) << 3];
    }
#pragma unroll
    for (int mi = 0; mi < 4; ++mi)
#pragma unroll
      for (int ni = 0; ni < 4; ++ni)
        acc[mi][ni] = __builtin_amdgcn_mfma_f32_16x16x32_f16(af[mi], bf[ni], acc[mi][ni], 0, 0, 0);
  }

  const int rbase = panel * 1024 + (rt << 7) + (wr << 6);
#pragma unroll
  for (int mi = 0; mi < 4; ++mi) {
#pragma unroll
    for (int reg = 0; reg < 4; ++reg) {
      float s = __expf(acc[mi][0][reg]) + __expf(acc[mi][1][reg]) +
                __expf(acc[mi][2][reg]) + __expf(acc[mi][3][reg]);
      s += __shfl_xor(s, 1, 64);
      s += __shfl_xor(s, 2, 64);
      s += __shfl_xor(s, 4, 64);
      s += __shfl_xor(s, 8, 64);
      if (lrow == 0) atomicAdd(&Z[rbase + (mi << 4) + (lk << 2) + reg], s);
    }
  }
}

// ---------------- K3: MFMA scores x4 levels -> product -> sparse emit ----
__global__ __launch_bounds__(256) void k_comb2(
    const _Float16* __restrict__ Qs, const _Float16* __restrict__ Ks,
    const float* __restrict__ Z, int* __restrict__ ccnt,
    unsigned short* __restrict__ cidx, float* __restrict__ cval)
{
  __shared__ __align__(16) _Float16 Asm[8192];
  __shared__ __align__(16) _Float16 Bsm[8192];
  __shared__ float Zl[128];
  __shared__ int lcnt[128];
  const int tid = threadIdx.x, lane = tid & 63, w = tid >> 6;
  const int wr = w >> 1, wc = w & 1;
  const int lrow = lane & 15, lk = lane >> 4;
  const int bid = blockIdx.x;
  const int ct = bid & 7, rt = (bid >> 3) & 7, bh = bid >> 6;
  const int b = bh >> 3, h = bh & 7;

  if (tid < 128) lcnt[tid] = 0;
  float prod[4][4][4];
#pragma unroll
  for (int mi = 0; mi < 4; ++mi)
#pragma unroll
    for (int ni = 0; ni < 4; ++ni)
#pragma unroll
      for (int r = 0; r < 4; ++r) prod[mi][ni][r] = 1.0f;

#pragma unroll 1
  for (int l = 0; l < 4; ++l) {
    __syncthreads();
    const int panel = b * 32 + l * 8 + h;
    stage_tile_s(Qs + (panel << 16) + (rt << 13), 64, Asm, tid);
    stage_tile_s(Ks + (panel << 16) + (ct << 13), 64, Bsm, tid);
    if (tid < 128) Zl[tid] = 1.0f / Z[panel * 1024 + (rt << 7) + tid];
    __syncthreads();

    f32x4 acc[4][4] = {};
    const int kstA[3] = {0, 0, 4}, kstB[3] = {0, 4, 0};
#pragma unroll
    for (int ks = 0; ks < 3; ++ks) {
      half8v af[4], bf[4];
#pragma unroll
      for (int mi = 0; mi < 4; ++mi) {
        const int row = (wr << 6) + (mi << 4) + lrow;
        const int xg = (kstA[ks] + lk) ^ (row & 7);
        af[mi] = *(const half8v*)&Asm[((row << 3) + xg) << 3];
      }
#pragma unroll
      for (int ni = 0; ni < 4; ++ni) {
        const int col = (wc << 6) + (ni << 4) + lrow;
        const int xg = (kstB[ks] + lk) ^ (col & 7);
        bf[ni] = *(const half8v*)&Bsm[((col << 3) + xg) << 3];
      }
#pragma unroll
      for (int mi = 0; mi < 4; ++mi)
#pragma unroll
        for (int ni = 0; ni < 4; ++ni)
          acc[mi][ni] = __builtin_amdgcn_mfma_f32_16x16x32_f16(af[mi], bf[ni], acc[mi][ni], 0, 0, 0);
    }

#pragma unroll
    for (int mi = 0; mi < 4; ++mi)
#pragma unroll
      for (int reg = 0; reg < 4; ++reg) {
        const float rcp = Zl[(wr << 6) + (mi << 4) + (lk << 2) + reg];
#pragma unroll
        for (int ni = 0; ni < 4; ++ni) {
          const float e = __expf(acc[mi][ni][reg]) * rcp - TTHR;
          prod[mi][ni][reg] *= fmaxf(e, 0.0f);
        }
      }
  }

  __syncthreads();
#pragma unroll
  for (int mi = 0; mi < 4; ++mi)
#pragma unroll
    for (int ni = 0; ni < 4; ++ni)
#pragma unroll
      for (int reg = 0; reg < 4; ++reg) {
        const float v = prod[mi][ni][reg];
        if (v > 0.0f) {
          const int rloc = (wr << 6) + (mi << 4) + (lk << 2) + reg;
          const int slot = atomicAdd(&lcnt[rloc], 1);
          if (slot < CAP) {
            const int rowc = (bh << 10) + (rt << 7) + rloc;
            const int mglob = (ct << 7) + (wc << 6) + (ni << 4) + lrow;
            cidx[(rowc * 8 + ct) * CAP + slot] = (unsigned short)mglob;
            cval[(rowc * 8 + ct) * CAP + slot] = v * YSCALE;
          }
        }
      }
  __syncthreads();
  if (tid < 128) {
    const int rowc = (bh << 10) + (rt << 7) + tid;
    ccnt[rowc * 8 + ct] = min(lcnt[tid], CAP);
  }
}

// ---------------- K4: sparse PV gather -> split-fp16 ys ----------------
__global__ __launch_bounds__(64) void k_pv(
    const float* __restrict__ Vp, const int* __restrict__ ccnt,
    const unsigned short* __restrict__ cidx, const float* __restrict__ cval,
    _Float16* __restrict__ ysh, _Float16* __restrict__ ysl)
{
  const int rowc = blockIdx.x;
  const int bh = rowc >> 10, n = rowc & 1023;
  const int b = bh >> 3, h = bh & 7;
  const int l0 = threadIdx.x >> 5, d = threadIdx.x & 31;
  const float* vA = Vp + ((b * 32 + l0 * 8 + h) << 15) + d;
  const float* vB = vA + (16 << 15);
  float y0 = 0.f, y1 = 0.f;
  for (int mcj = 0; mcj < 8; ++mcj) {
    const int cnt = ccnt[rowc * 8 + mcj];
    const int off = (rowc * 8 + mcj) * CAP;
    for (int i = 0; i < cnt; ++i) {
      const int m = cidx[off + i];
      const float w = cval[off + i];
      y0 = fmaf(w, vA[m * 32], y0);
      y1 = fmaf(w, vB[m * 32], y1);
    }
  }
  const int idx = ((b << 10) + n) * 1024 + l0 * 256 + h * 32 + d;
  _Float16 h0 = (_Float16)y0;
  ysh[idx] = h0;
  ysl[idx] = (_Float16)(y0 - (float)h0);
  _Float16 h1 = (_Float16)y1;
  ysh[idx + 512] = h1;
  ysl[idx + 512] = (_Float16)(y1 - (float)h1);
}

extern "C" void kernel_launch(void* const* d_in, const int* in_sizes, int n_in,
                              void* d_out, int out_size, void* d_ws, size_t ws_size,
                              hipStream_t stream)
{
  const float* x  = (const float*)d_in[0];
  const float* Wc = (const float*)d_in[1];
  const float* bc = (const float*)d_in[2];
  const float* Wp = (const float*)d_in[3];
  const float* bp = (const float*)d_in[4];
  float* out = (float*)d_out;
  (void)in_sizes; (void)n_in; (void)out_size;

  // ws layout (bytes):
  // Vp   @ 0          16 MB   fp32 [128][1024][32]
  // Qs   @ 16777216   16 MB   fp16 [128][1024][64] (hi|lo)
  // Ks   @ 33554432   16 MB
  // Z    @ 50331648   512 KB  fp32 [128][1024]
  // xh/ysh @ 50855936 8 MB    fp16 (x: [16384][256]; ys: [4096][1024]) -- disjoint lifetimes
  // xl/ysl @ 59244544 8 MB
  // ccnt @ 67633152   1 MB    int [32768][8]
  // cidx @ 68681728   8 MB    ushort [32768][8][16]
  // cval @ 77070336   16 MB   fp32
  // Wch  @ 93847552   384 KB  fp16 [768][256]
  // Wcl  @ 94240768   384 KB
  // Wph  @ 94633984   2 MB    fp16 [1024][1024]
  // Wpl  @ 96731136   2 MB    (end 98828288)
  if (ws_size < 98828288ull) return;
  char* wsb = (char*)d_ws;
  float*          Vp   = (float*)wsb;
  _Float16*       Qs   = (_Float16*)(wsb + 16777216);
  _Float16*       Ks   = (_Float16*)(wsb + 33554432);
  float*          Z    = (float*)(wsb + 50331648);
  _Float16*       xh   = (_Float16*)(wsb + 50855936);
  _Float16*       xl   = (_Float16*)(wsb + 59244544);
  int*            ccnt = (int*)(wsb + 67633152);
  unsigned short* cidx = (unsigned short*)(wsb + 68681728);
  float*          cval = (float*)(wsb + 77070336);
  _Float16*       Wch  = (_Float16*)(wsb + 93847552);
  _Float16*       Wcl  = (_Float16*)(wsb + 94240768);
  _Float16*       Wph  = (_Float16*)(wsb + 94633984);
  _Float16*       Wpl  = (_Float16*)(wsb + 96731136);

  hipMemsetAsync(Z, 0, 524288, stream);
  k_split_rm<<<dim3(4096), dim3(256), 0, stream>>>(x, xh, xl, 1048576);
  k_split_tr<<<dim3(192), dim3(256), 0, stream>>>(Wc, Wch, Wcl, 256, 768);
  k_split_tr<<<dim3(1024), dim3(256), 0, stream>>>(Wp, Wph, Wpl, 1024, 1024);
  // qkv: M=16384 K=256 N=768 ; kclog=2 (4 chunks/phase), nbn=6
  k_gemm_split<1><<<dim3(768), dim3(256), 0, stream>>>(
      xh, xl, Wch, Wcl, bc, 256, 2, 6, nullptr, Qs, Ks, Vp);
  k_score_sum<<<dim3(8192), dim3(256), 0, stream>>>(Qs, Ks, Z);
  k_comb2<<<dim3(2048), dim3(256), 0, stream>>>(Qs, Ks, Z, ccnt, cidx, cval);
  k_pv<<<dim3(32768), dim3(64), 0, stream>>>(Vp, ccnt, cidx, cval, xh, xl);
  // proj: M=4096 K=1024 N=1024 ; kclog=4 (16 chunks/phase), nbn=8
  k_gemm_split<0><<<dim3(256), dim3(256), 0, stream>>>(
      xh, xl, Wph, Wpl, bp, 1024, 4, 8, out, nullptr, nullptr, nullptr);
}

// Round 4
// 236.730 us; speedup vs baseline: 3.0892x; 1.1730x over previous
//
#include <hip/hip_runtime.h>

#define TTHR 0.001f
#define QSCALE 0.17677669529663687f   // 1/sqrt(32)
#define CAP 16
#define YSCALE 8388608.0f             // 2^23
#define YINV   1.1920928955078125e-07f // 2^-23

typedef _Float16 half4v __attribute__((ext_vector_type(4)));
typedef _Float16 half8v __attribute__((ext_vector_type(8)));
typedef float f32x4 __attribute__((ext_vector_type(4)));

// ---- stage a 128x64-half tile into LDS, XOR-swizzled, arbitrary row stride ----
// LDS granule (row, x) holds source granule (row, x ^ (row&7)); 16B granules.
// global_load_lds writes linearly (wave base + lane*16) -> inverse perm on source.
__device__ __forceinline__ void stage_tile_s(const _Float16* __restrict__ gsrc,
                                             int rowstride, _Float16* lds, int tid)
{
  const int lane = tid & 63;
  const int w4 = (tid >> 6) << 2;
#pragma unroll
  for (int r = 0; r < 4; ++r) {
    const int p = (w4 + r) * 64 + lane;
    const int row = p >> 3, xg = p & 7;
    __builtin_amdgcn_global_load_lds(
        (const __attribute__((address_space(1))) void*)(gsrc + row * rowstride + ((xg ^ (row & 7)) << 3)),
        (__attribute__((address_space(3))) void*)(lds + (w4 + r) * 512),
        16, 0, 0);
  }
}

// ---------------- conversion kernels ----------------
__global__ __launch_bounds__(256) void k_split_rm(
    const float* __restrict__ in, _Float16* __restrict__ oh,
    _Float16* __restrict__ ol, int n4)
{
  const int i = blockIdx.x * 256 + threadIdx.x;
  if (i >= n4) return;
  float4 v = ((const float4*)in)[i];
  half4v h = {(_Float16)v.x, (_Float16)v.y, (_Float16)v.z, (_Float16)v.w};
  half4v l = {(_Float16)(v.x - (float)h[0]), (_Float16)(v.y - (float)h[1]),
              (_Float16)(v.z - (float)h[2]), (_Float16)(v.w - (float)h[3])};
  ((half4v*)oh)[i] = h;
  ((half4v*)ol)[i] = l;
}

__global__ __launch_bounds__(256) void k_split_tr(
    const float* __restrict__ in, _Float16* __restrict__ oh,
    _Float16* __restrict__ ol, int K, int N)
{
  __shared__ float t[32][33];
  const int nb = N >> 5;
  const int n0 = (blockIdx.x % nb) << 5, k0 = (blockIdx.x / nb) << 5;
  const int r = threadIdx.x >> 3, c4 = (threadIdx.x & 7) << 2;
  float4 v = *(const float4*)&in[(k0 + r) * N + n0 + c4];
  t[r][c4] = v.x; t[r][c4 + 1] = v.y; t[r][c4 + 2] = v.z; t[r][c4 + 3] = v.w;
  __syncthreads();
  float a0 = t[c4][r], a1 = t[c4 + 1][r], a2 = t[c4 + 2][r], a3 = t[c4 + 3][r];
  half4v h = {(_Float16)a0, (_Float16)a1, (_Float16)a2, (_Float16)a3};
  half4v l = {(_Float16)(a0 - (float)h[0]), (_Float16)(a1 - (float)h[1]),
              (_Float16)(a2 - (float)h[2]), (_Float16)(a3 - (float)h[3])};
  *(half4v*)&oh[(n0 + r) * K + k0 + c4] = h;
  *(half4v*)&ol[(n0 + r) * K + k0 + c4] = l;
}

// ---------------- generic split-fp16 MFMA GEMM (2-phase dbuf) ----------------
template<int EPI>
__global__ __launch_bounds__(256) void k_gemm_split(
    const _Float16* __restrict__ Ah, const _Float16* __restrict__ Al,
    const _Float16* __restrict__ Bh, const _Float16* __restrict__ Bl,
    const float* __restrict__ bias, int K, int kclog, int nbn,
    float* __restrict__ out, _Float16* __restrict__ Qs,
    _Float16* __restrict__ Ks, float* __restrict__ Vp)
{
  __shared__ __align__(16) _Float16 Asm[2][8192];
  __shared__ __align__(16) _Float16 Bsm[2][8192];
  const int tid = threadIdx.x, lane = tid & 63, w = tid >> 6;
  const int wr = w >> 1, wc = w & 1;
  const int lrow = lane & 15, lk = lane >> 4;
  const int mt = blockIdx.x / nbn, ct = blockIdx.x % nbn;
  const int m0 = mt << 7, c0 = ct << 7;

  const int nch = 3 << kclog;
  const int kcm = (1 << kclog) - 1;
  stage_tile_s(Ah + (size_t)m0 * K, K, Asm[0], tid);
  stage_tile_s(Bh + (size_t)c0 * K, K, Bsm[0], tid);
  __syncthreads();

  f32x4 acc[4][4] = {};
#pragma unroll 1
  for (int ch = 0; ch < nch; ++ch) {
    const int cur = ch & 1;
    if (ch + 1 < nch) {
      const int ch2 = ch + 1;
      const int phase = ch2 >> kclog, kc = ch2 & kcm;
      const _Float16* As = (phase == 2) ? Al : Ah;
      const _Float16* Bs = (phase == 1) ? Bl : Bh;
      stage_tile_s(As + (size_t)m0 * K + (kc << 6), K, Asm[cur ^ 1], tid);
      stage_tile_s(Bs + (size_t)c0 * K + (kc << 6), K, Bsm[cur ^ 1], tid);
    }
#pragma unroll
    for (int ks = 0; ks < 2; ++ks) {
      half8v af[4], bf[4];
#pragma unroll
      for (int mi = 0; mi < 4; ++mi) {
        const int row = (wr << 6) + (mi << 4) + lrow;
        const int xg = ((ks << 2) + lk) ^ (row & 7);
        af[mi] = *(const half8v*)&Asm[cur][((row << 3) + xg) << 3];
      }
#pragma unroll
      for (int ni = 0; ni < 4; ++ni) {
        const int col = (wc << 6) + (ni << 4) + lrow;
        const int xg = ((ks << 2) + lk) ^ (col & 7);
        bf[ni] = *(const half8v*)&Bsm[cur][((col << 3) + xg) << 3];
      }
#pragma unroll
      for (int mi = 0; mi < 4; ++mi)
#pragma unroll
        for (int ni = 0; ni < 4; ++ni)
          acc[mi][ni] = __builtin_amdgcn_mfma_f32_16x16x32_f16(af[mi], bf[ni], acc[mi][ni], 0, 0, 0);
    }
    __syncthreads();
  }

#pragma unroll
  for (int ni = 0; ni < 4; ++ni) {
    const int c = c0 + (wc << 6) + (ni << 4) + lrow;
    const float bv = bias[c];
    if (EPI == 0) {
#pragma unroll
      for (int mi = 0; mi < 4; ++mi)
#pragma unroll
        for (int reg = 0; reg < 4; ++reg) {
          const int m = m0 + (wr << 6) + (mi << 4) + (lk << 2) + reg;
          out[m * 1024 + c] = acc[mi][ni][reg] * YINV + bv;
        }
    } else {
      const int part = c >> 8, cc = c & 255;
      const int h = cc >> 5, d = cc & 31;
#pragma unroll
      for (int mi = 0; mi < 4; ++mi)
#pragma unroll
        for (int reg = 0; reg < 4; ++reg) {
          const int m = m0 + (wr << 6) + (mi << 4) + (lk << 2) + reg;
          const int b = m >> 12, n = (m >> 2) & 1023, l = m & 3;
          const int panel = b * 32 + l * 8 + h;
          float v = acc[mi][ni][reg] + bv;
          if (part == 2) {
            Vp[(panel << 15) + n * 32 + d] = v;
          } else {
            _Float16* dst = part ? Ks : Qs;
            if (!part) v *= QSCALE;
            _Float16 hv = (_Float16)v;
            _Float16 lv = (_Float16)(v - (float)hv);
            dst[(panel << 16) + n * 64 + d] = hv;
            dst[(panel << 16) + n * 64 + 32 + d] = lv;
          }
        }
    }
  }
}

// ---------------- K2: scores -> exp -> row sums Z (per-row blocks) ----------
// grid: panel(128) x rowtile(8); Q staged once, K tiles double-buffered.
__global__ __launch_bounds__(256) void k_score_sum(
    const _Float16* __restrict__ Qs, const _Float16* __restrict__ Ks,
    float* __restrict__ Z)
{
  __shared__ __align__(16) _Float16 Qsm[8192];
  __shared__ __align__(16) _Float16 Ksm[2][8192];
  __shared__ float Zsh[128];
  const int tid = threadIdx.x, lane = tid & 63, w = tid >> 6;
  const int wr = w >> 1, wc = w & 1;
  const int lrow = lane & 15, lk = lane >> 4;
  const int rt = blockIdx.x & 7, panel = blockIdx.x >> 3;

  stage_tile_s(Qs + (panel << 16) + (rt << 13), 64, Qsm, tid);
  stage_tile_s(Ks + (panel << 16), 64, Ksm[0], tid);
  if (tid < 128) Zsh[tid] = 0.0f;
  __syncthreads();

  const int kstA[3] = {0, 0, 4}, kstB[3] = {0, 4, 0};
  half8v af[3][4];
#pragma unroll
  for (int ks = 0; ks < 3; ++ks)
#pragma unroll
    for (int mi = 0; mi < 4; ++mi) {
      const int row = (wr << 6) + (mi << 4) + lrow;
      const int xg = (kstA[ks] + lk) ^ (row & 7);
      af[ks][mi] = *(const half8v*)&Qsm[((row << 3) + xg) << 3];
    }

  float rsum[4][4] = {};
#pragma unroll 1
  for (int ct = 0; ct < 8; ++ct) {
    const int cur = ct & 1;
    if (ct < 7)
      stage_tile_s(Ks + (panel << 16) + ((ct + 1) << 13), 64, Ksm[cur ^ 1], tid);
    f32x4 acc[4][4] = {};
#pragma unroll
    for (int ks = 0; ks < 3; ++ks) {
      half8v bf[4];
#pragma unroll
      for (int ni = 0; ni < 4; ++ni) {
        const int col = (wc << 6) + (ni << 4) + lrow;
        const int xg = (kstB[ks] + lk) ^ (col & 7);
        bf[ni] = *(const half8v*)&Ksm[cur][((col << 3) + xg) << 3];
      }
#pragma unroll
      for (int mi = 0; mi < 4; ++mi)
#pragma unroll
        for (int ni = 0; ni < 4; ++ni)
          acc[mi][ni] = __builtin_amdgcn_mfma_f32_16x16x32_f16(af[ks][mi], bf[ni], acc[mi][ni], 0, 0, 0);
    }
#pragma unroll
    for (int mi = 0; mi < 4; ++mi)
#pragma unroll
      for (int reg = 0; reg < 4; ++reg)
#pragma unroll
        for (int ni = 0; ni < 4; ++ni)
          rsum[mi][reg] += __expf(acc[mi][ni][reg]);
    __syncthreads();
  }

#pragma unroll
  for (int mi = 0; mi < 4; ++mi)
#pragma unroll
    for (int reg = 0; reg < 4; ++reg) {
      float s = rsum[mi][reg];
      s += __shfl_xor(s, 1, 64);
      s += __shfl_xor(s, 2, 64);
      s += __shfl_xor(s, 4, 64);
      s += __shfl_xor(s, 8, 64);
      if (lrow == 0) atomicAdd(&Zsh[(wr << 6) + (mi << 4) + (lk << 2) + reg], s);
    }
  __syncthreads();
  if (tid < 128) Z[panel * 1024 + (rt << 7) + tid] = Zsh[tid];
}

// ---------------- K3: scores x4 levels -> product -> sparse emit (dbuf) ----
// prod_l relu(exp(s)/Z - T) == (prod_l max(exp(s) - T*Z_l, 0)) / prod_l Z_l
__global__ __launch_bounds__(256) void k_comb2(
    const _Float16* __restrict__ Qs, const _Float16* __restrict__ Ks,
    const float* __restrict__ Z, int* __restrict__ ccnt,
    unsigned short* __restrict__ cidx, float* __restrict__ cval)
{
  __shared__ __align__(16) _Float16 Asm[2][8192];
  __shared__ __align__(16) _Float16 Bsm[2][8192];
  __shared__ float tzl[2][128];
  __shared__ float rzl[128];
  __shared__ int lcnt[128];
  const int tid = threadIdx.x, lane = tid & 63, w = tid >> 6;
  const int wr = w >> 1, wc = w & 1;
  const int lrow = lane & 15, lk = lane >> 4;
  const int bid = blockIdx.x;
  const int ct = bid & 7, rt = (bid >> 3) & 7, bh = bid >> 6;
  const int b = bh >> 3, h = bh & 7;

  if (tid < 128) {
    lcnt[tid] = 0;
    const float* zp = Z + (b * 32 + h) * 1024 + (rt << 7) + tid;
    float z0 = zp[0], z1 = zp[8192], z2 = zp[16384], z3 = zp[24576];
    rzl[tid] = 1.0f / ((z0 * z1) * (z2 * z3));
    tzl[0][tid] = TTHR * z0;
  }
  {
    const int panel = b * 32 + h;
    stage_tile_s(Qs + (panel << 16) + (rt << 13), 64, Asm[0], tid);
    stage_tile_s(Ks + (panel << 16) + (ct << 13), 64, Bsm[0], tid);
  }
  __syncthreads();

  float prod[4][4][4];
#pragma unroll
  for (int mi = 0; mi < 4; ++mi)
#pragma unroll
    for (int ni = 0; ni < 4; ++ni)
#pragma unroll
      for (int r = 0; r < 4; ++r) prod[mi][ni][r] = 1.0f;

  const int kstA[3] = {0, 0, 4}, kstB[3] = {0, 4, 0};
#pragma unroll 1
  for (int l = 0; l < 4; ++l) {
    const int cur = l & 1;
    if (l < 3) {
      const int panel = b * 32 + (l + 1) * 8 + h;
      stage_tile_s(Qs + (panel << 16) + (rt << 13), 64, Asm[cur ^ 1], tid);
      stage_tile_s(Ks + (panel << 16) + (ct << 13), 64, Bsm[cur ^ 1], tid);
      if (tid < 128) tzl[cur ^ 1][tid] = TTHR * Z[panel * 1024 + (rt << 7) + tid];
    }

    f32x4 acc[4][4] = {};
#pragma unroll
    for (int ks = 0; ks < 3; ++ks) {
      half8v af[4], bf[4];
#pragma unroll
      for (int mi = 0; mi < 4; ++mi) {
        const int row = (wr << 6) + (mi << 4) + lrow;
        const int xg = (kstA[ks] + lk) ^ (row & 7);
        af[mi] = *(const half8v*)&Asm[cur][((row << 3) + xg) << 3];
      }
#pragma unroll
      for (int ni = 0; ni < 4; ++ni) {
        const int col = (wc << 6) + (ni << 4) + lrow;
        const int xg = (kstB[ks] + lk) ^ (col & 7);
        bf[ni] = *(const half8v*)&Bsm[cur][((col << 3) + xg) << 3];
      }
#pragma unroll
      for (int mi = 0; mi < 4; ++mi)
#pragma unroll
        for (int ni = 0; ni < 4; ++ni)
          acc[mi][ni] = __builtin_amdgcn_mfma_f32_16x16x32_f16(af[mi], bf[ni], acc[mi][ni], 0, 0, 0);
    }

#pragma unroll
    for (int mi = 0; mi < 4; ++mi)
#pragma unroll
      for (int reg = 0; reg < 4; ++reg) {
        const float tz = tzl[cur][(wr << 6) + (mi << 4) + (lk << 2) + reg];
#pragma unroll
        for (int ni = 0; ni < 4; ++ni) {
          const float e = __expf(acc[mi][ni][reg]) - tz;
          prod[mi][ni][reg] *= fmaxf(e, 0.0f);
        }
      }
    __syncthreads();
  }

#pragma unroll
  for (int mi = 0; mi < 4; ++mi)
#pragma unroll
    for (int ni = 0; ni < 4; ++ni)
#pragma unroll
      for (int reg = 0; reg < 4; ++reg) {
        const int rloc = (wr << 6) + (mi << 4) + (lk << 2) + reg;
        const float v = prod[mi][ni][reg] * rzl[rloc];
        if (v > 0.0f) {
          const int slot = atomicAdd(&lcnt[rloc], 1);
          if (slot < CAP) {
            const int rowc = (bh << 10) + (rt << 7) + rloc;
            const int mglob = (ct << 7) + (wc << 6) + (ni << 4) + lrow;
            cidx[(rowc * 8 + ct) * CAP + slot] = (unsigned short)mglob;
            cval[(rowc * 8 + ct) * CAP + slot] = v * YSCALE;
          }
        }
      }
  __syncthreads();
  if (tid < 128) {
    const int rowc = (bh << 10) + (rt << 7) + tid;
    ccnt[rowc * 8 + ct] = min(lcnt[tid], CAP);
  }
}

// ---------------- K4: sparse PV gather -> split-fp16 ys ----------------
__global__ __launch_bounds__(64) void k_pv(
    const float* __restrict__ Vp, const int* __restrict__ ccnt,
    const unsigned short* __restrict__ cidx, const float* __restrict__ cval,
    _Float16* __restrict__ ysh, _Float16* __restrict__ ysl)
{
  const int rowc = blockIdx.x;
  const int bh = rowc >> 10, n = rowc & 1023;
  const int b = bh >> 3, h = bh & 7;
  const int l0 = threadIdx.x >> 5, d = threadIdx.x & 31;
  const float* vA = Vp + ((b * 32 + l0 * 8 + h) << 15) + d;
  const float* vB = vA + (16 << 15);
  float y0 = 0.f, y1 = 0.f;
  for (int mcj = 0; mcj < 8; ++mcj) {
    const int cnt = ccnt[rowc * 8 + mcj];
    const int off = (rowc * 8 + mcj) * CAP;
    for (int i = 0; i < cnt; ++i) {
      const int m = cidx[off + i];
      const float w = cval[off + i];
      y0 = fmaf(w, vA[m * 32], y0);
      y1 = fmaf(w, vB[m * 32], y1);
    }
  }
  const int idx = ((b << 10) + n) * 1024 + l0 * 256 + h * 32 + d;
  _Float16 h0 = (_Float16)y0;
  ysh[idx] = h0;
  ysl[idx] = (_Float16)(y0 - (float)h0);
  _Float16 h1 = (_Float16)y1;
  ysh[idx + 512] = h1;
  ysl[idx + 512] = (_Float16)(y1 - (float)h1);
}

extern "C" void kernel_launch(void* const* d_in, const int* in_sizes, int n_in,
                              void* d_out, int out_size, void* d_ws, size_t ws_size,
                              hipStream_t stream)
{
  const float* x  = (const float*)d_in[0];
  const float* Wc = (const float*)d_in[1];
  const float* bc = (const float*)d_in[2];
  const float* Wp = (const float*)d_in[3];
  const float* bp = (const float*)d_in[4];
  float* out = (float*)d_out;
  (void)in_sizes; (void)n_in; (void)out_size;

  if (ws_size < 98828288ull) return;
  char* wsb = (char*)d_ws;
  float*          Vp   = (float*)wsb;
  _Float16*       Qs   = (_Float16*)(wsb + 16777216);
  _Float16*       Ks   = (_Float16*)(wsb + 33554432);
  float*          Z    = (float*)(wsb + 50331648);
  _Float16*       xh   = (_Float16*)(wsb + 50855936);
  _Float16*       xl   = (_Float16*)(wsb + 59244544);
  int*            ccnt = (int*)(wsb + 67633152);
  unsigned short* cidx = (unsigned short*)(wsb + 68681728);
  float*          cval = (float*)(wsb + 77070336);
  _Float16*       Wch  = (_Float16*)(wsb + 93847552);
  _Float16*       Wcl  = (_Float16*)(wsb + 94240768);
  _Float16*       Wph  = (_Float16*)(wsb + 94633984);
  _Float16*       Wpl  = (_Float16*)(wsb + 96731136);

  k_split_rm<<<dim3(4096), dim3(256), 0, stream>>>(x, xh, xl, 1048576);
  k_split_tr<<<dim3(192), dim3(256), 0, stream>>>(Wc, Wch, Wcl, 256, 768);
  k_split_tr<<<dim3(1024), dim3(256), 0, stream>>>(Wp, Wph, Wpl, 1024, 1024);
  k_gemm_split<1><<<dim3(768), dim3(256), 0, stream>>>(
      xh, xl, Wch, Wcl, bc, 256, 2, 6, nullptr, Qs, Ks, Vp);
  k_score_sum<<<dim3(1024), dim3(256), 0, stream>>>(Qs, Ks, Z);
  k_comb2<<<dim3(2048), dim3(256), 0, stream>>>(Qs, Ks, Z, ccnt, cidx, cval);
  k_pv<<<dim3(32768), dim3(64), 0, stream>>>(Vp, ccnt, cidx, cval, xh, xl);
  k_gemm_split<0><<<dim3(256), dim3(256), 0, stream>>>(
      xh, xl, Wph, Wpl, bp, 1024, 4, 8, out, nullptr, nullptr, nullptr);
}